// Round 4
// baseline (547.889 us; speedup 1.0000x reference)
//
#include <hip/hip_runtime.h>

typedef __bf16 bf16_t;
typedef __bf16 bf16x8_t __attribute__((ext_vector_type(8)));
typedef __bf16 bf16x4_t __attribute__((ext_vector_type(4)));
typedef float f32x4_t __attribute__((ext_vector_type(4)));
typedef unsigned short u16;
typedef unsigned int u32;

#define B_ 2
#define S_ 4096
#define NH_ 16
#define NKV_ 4
#define D_ 128
#define NEG_ (-1000000000.0f)
#define SCALE_ 0.08838834764831845f

// async global->LDS, 16B per lane; LDS dest must be wave-uniform base (+lane*16 implicit)
__device__ __forceinline__ void load16(const bf16_t* g, bf16_t* l) {
  __builtin_amdgcn_global_load_lds(
      (__attribute__((address_space(1))) void*)(g),
      (__attribute__((address_space(3))) void*)(l),
      16, 0, 0);
}

// ---------------- fused fp32 -> bf16 convert (all 5 tensors, one launch) ----------------
__global__ __launch_bounds__(256) void cvt_all_kernel(const float* __restrict__ hs,
                                                      const float* __restrict__ Wq,
                                                      const float* __restrict__ Wk,
                                                      const float* __restrict__ Wv,
                                                      const float* __restrict__ Wo,
                                                      bf16_t* __restrict__ Xb,
                                                      bf16_t* __restrict__ Wb,
                                                      bf16_t* __restrict__ Wob) {
  int i = blockIdx.x * 256 + threadIdx.x;  // float4 index; ranges are 256-aligned (uniform branch)
  const float* src; bf16_t* dst; int local;
  if (i < 4194304)      { src = hs; dst = Xb;            local = i; }
  else if (i < 5242880) { src = Wq; dst = Wb;            local = i - 4194304; }
  else if (i < 5505024) { src = Wk; dst = Wb + 4194304;  local = i - 5242880; }
  else if (i < 5767168) { src = Wv; dst = Wb + 5242880;  local = i - 5505024; }
  else                  { src = Wo; dst = Wob;           local = i - 5767168; }
  float4 v = ((const float4*)src)[local];
  bf16x4_t o;
  o.x = (bf16_t)v.x; o.y = (bf16_t)v.y; o.z = (bf16_t)v.z; o.w = (bf16_t)v.w;
  *(bf16x4_t*)(dst + (size_t)local * 4) = o;
}

// ---------------- GEMM: C(MxN) = A(MxK) @ B(NxK)^T, bf16 in, fp32 acc ----------------
// m97 structure + XOR-swizzled LDS image: chunk (row,c) lives at slot c^((row>>1)&3)
// -> fragment ds_read_b128 is 2-way (free) instead of 8-way.
template <int BF16OUT>
__global__ __launch_bounds__(256) void gemm_bt_kernel(const bf16_t* __restrict__ A,
                                                      const bf16_t* __restrict__ Bm,
                                                      float* __restrict__ Cf,
                                                      bf16_t* __restrict__ Cb,
                                                      int M, int N, int K) {
  __shared__ bf16_t As[128 * 32];
  __shared__ bf16_t Bs[128 * 32];
  const int t = threadIdx.x;
  const int lane = t & 63;
  const int w = t >> 6;
  const int wr = w >> 1, wc = w & 1;
  const int l15 = lane & 15, l4 = lane >> 4;
  const int m0 = blockIdx.x * 128;
  const int n0 = blockIdx.y * 128;
  const int xr = (l15 >> 1) & 3;   // fragment-read XOR term

  f32x4_t acc[4][4] = {};

  for (int k0 = 0; k0 < K; k0 += 32) {
    __syncthreads();
#pragma unroll
    for (int i = 0; i < 2; i++) {
      int f = t + 256 * i;
      int row = f >> 2, cl = f & 3;
      int cg = cl ^ ((row >> 1) & 3);   // global chunk that belongs in LDS slot cl
      load16(A + (size_t)(m0 + row) * K + k0 + cg * 8, As + (w * 64 + i * 256) * 8);
      load16(Bm + (size_t)(n0 + row) * K + k0 + cg * 8, Bs + (w * 64 + i * 256) * 8);
    }
    __syncthreads();
    bf16x8_t af[4], bfr[4];
#pragma unroll
    for (int mi = 0; mi < 4; mi++) {
      int ra = wr * 64 + mi * 16 + l15;
      af[mi] = *(const bf16x8_t*)&As[(ra * 4 + (l4 ^ xr)) * 8];
    }
#pragma unroll
    for (int ni = 0; ni < 4; ni++) {
      int rb = wc * 64 + ni * 16 + l15;
      bfr[ni] = *(const bf16x8_t*)&Bs[(rb * 4 + (l4 ^ xr)) * 8];
    }
#pragma unroll
    for (int mi = 0; mi < 4; mi++)
#pragma unroll
      for (int ni = 0; ni < 4; ni++)
        acc[mi][ni] = __builtin_amdgcn_mfma_f32_16x16x32_bf16(af[mi], bfr[ni], acc[mi][ni], 0, 0, 0);
  }

#pragma unroll
  for (int mi = 0; mi < 4; mi++)
#pragma unroll
    for (int ni = 0; ni < 4; ni++)
#pragma unroll
      for (int r = 0; r < 4; r++) {
        int grow = m0 + wr * 64 + mi * 16 + l4 * 4 + r;
        int gcol = n0 + wc * 64 + ni * 16 + l15;
        float v = acc[mi][ni][r];
        if (BF16OUT) Cb[(size_t)grow * N + gcol] = (bf16_t)v;
        else Cf[(size_t)grow * N + gcol] = v;
      }
}

// ---------------- RoPE + swizzled head layout for q,k ----------------
// Qro per (b,h,sblock): [lc(16)][row(64)][8]  where lc = d/8  (16 KB per block)
__global__ __launch_bounds__(320) void rope_kernel(const bf16_t* __restrict__ qkv,
                                                   const float* __restrict__ cosp,
                                                   const float* __restrict__ sinp,
                                                   bf16_t* __restrict__ Qro,
                                                   bf16_t* __restrict__ Kro) {
  const int tk = blockIdx.x;      // 0..8191 token
  const int b = tk >> 12;
  const int s = tk & 4095;
  const int sblock = s >> 6, row = s & 63;
  const int idx = threadIdx.x;    // 0..319: 256 q-chunks + 64 k-chunks
  int head, lc;
  const bf16_t* base;
  bf16_t* outp;
  if (idx < 256) {
    head = idx >> 4; lc = idx & 15;
    base = qkv + (size_t)tk * 3072 + head * 128;
    outp = Qro + ((size_t)(b * NH_ + head) * 64 + sblock) * 8192;
  } else {
    int i2 = idx - 256;
    head = i2 >> 4; lc = i2 & 15;
    base = qkv + (size_t)tk * 3072 + 2048 + head * 128;
    outp = Kro + ((size_t)(b * NKV_ + head) * 64 + sblock) * 8192;
  }
  const int d0 = lc * 8;
  bf16x8_t x = *(const bf16x8_t*)(base + d0);
  const int d0p = (d0 < 64) ? d0 + 64 : d0 - 64;
  bf16x8_t xp = *(const bf16x8_t*)(base + d0p);
  const float sgn = (d0 < 64) ? -1.0f : 1.0f;
  const float* cb = cosp + (size_t)tk * 128 + d0;
  const float* sb = sinp + (size_t)tk * 128 + d0;
  bf16x8_t o;
#pragma unroll
  for (int e = 0; e < 8; e++)
    o[e] = (bf16_t)((float)x[e] * cb[e] + sgn * (float)xp[e] * sb[e]);
  *(bf16x8_t*)(outp + (lc * 64 + row) * 8) = o;
}

// ---------------- V transpose into swizzled layout ----------------
// Vt per (b,kh,sblock): [sc(8)][d(128)][8]  where chunk content e runs along s
__global__ __launch_bounds__(256) void vtrans_kernel(const u16* __restrict__ qkv,
                                                     u16* __restrict__ vt) {
  __shared__ u16 tile[64][136];   // [s][d], d padded 128->136
  const int sblock = blockIdx.x;
  const int kh = blockIdx.y;
  const int b = blockIdx.z;
  const int t = threadIdx.x;
#pragma unroll
  for (int i = 0; i < 4; i++) {
    int f = t + 256 * i;
    int sl = f >> 4, c = f & 15;
    uint4 vv = *(const uint4*)(qkv + (size_t)(b * S_ + sblock * 64 + sl) * 3072 + 2560 + kh * 128 + c * 8);
    *(uint4*)&tile[sl][c * 8] = vv;
  }
  __syncthreads();
  u16* out = vt + ((size_t)(b * NKV_ + kh) * 64 + sblock) * 8192;
#pragma unroll
  for (int i = 0; i < 4; i++) {
    int g = t + 256 * i;
    int sc = g >> 7, d = g & 127;
    u16 e0 = tile[sc * 8 + 0][d], e1 = tile[sc * 8 + 1][d];
    u16 e2 = tile[sc * 8 + 2][d], e3 = tile[sc * 8 + 3][d];
    u16 e4 = tile[sc * 8 + 4][d], e5 = tile[sc * 8 + 5][d];
    u16 e6 = tile[sc * 8 + 6][d], e7 = tile[sc * 8 + 7][d];
    uint4 ov;
    ov.x = (u32)e0 | ((u32)e1 << 16);
    ov.y = (u32)e2 | ((u32)e3 << 16);
    ov.z = (u32)e4 | ((u32)e5 << 16);
    ov.w = (u32)e6 | ((u32)e7 << 16);
    *(uint4*)(out + (size_t)g * 8) = ov;
  }
}

// ---------------- GQA-packed block-sparse flash attention ----------------
// one WG of 256 threads per (qblock, kv-head, head-pair, batch): 4 waves x 2
// row-tiles = 128 q-rows (2 heads x 64). 41 KB LDS + launch_bounds(256,3)
// -> 3 WGs/CU so barrier stalls overlap across WGs.
__global__ __launch_bounds__(256, 3) void attn_kernel(const bf16_t* __restrict__ Qr,
                                                      const bf16_t* __restrict__ Kr,
                                                      const bf16_t* __restrict__ Vt,
                                                      bf16_t* __restrict__ Ao) {
  __shared__ bf16_t Ks[8192];            // 16 KB [lc16][row64][8]
  __shared__ bf16_t Vs[8192];            // 16 KB [sc8][d128][8]
  __shared__ bf16_t Ps[4 * 16 * 72];     // 9 KB: per-wave 16x72 padded, reused across mt
  const int qid = blockIdx.x;
  const int kh = blockIdx.y >> 1;
  const int hp = blockIdx.y & 1;
  const int b = blockIdx.z;
  const int t = threadIdx.x;
  const int lane = t & 63;
  const int w = t >> 6;                  // 0..3
  const int l15 = lane & 15, l4 = lane >> 4;
  const int h = kh * 4 + hp * 2 + (w >> 1);   // wave-uniform head
  int row0[2];
  row0[0] = ((w * 2) & 3) * 16;
  row0[1] = ((w * 2 + 1) & 3) * 16;

  // kept-block mask (uniform per WG)
  int keep_mask = 0;
#pragma unroll
  for (int j = 0; j < 12; j++) {
    int cj;
    if (j < 4) cj = j * 16;
    else { cj = qid - 11 + j; cj = cj < 0 ? 0 : cj; cj = cj > 63 ? 63 : cj; }
    bool keep = (cj <= qid);
#pragma unroll
    for (int i = 0; i < j; i++) {
      int ci;
      if (i < 4) ci = i * 16;
      else { ci = qid - 11 + i; ci = ci < 0 ? 0 : ci; ci = ci > 63 ? 63 : ci; }
      if (ci == cj) keep = false;
    }
    if (keep) keep_mask |= (1 << j);
  }

  const bf16_t* Qg = Qr + ((size_t)(b * NH_ + h) * 64 + qid) * 8192;
  const bf16_t* Kg = Kr + ((size_t)(b * NKV_ + kh) * 64) * 8192;
  const bf16_t* Vg = Vt + ((size_t)(b * NKV_ + kh) * 64) * 8192;

  // Q fragments straight from global (coalesced 256B runs), persistent
  bf16x8_t qa[2][4];
#pragma unroll
  for (int mt = 0; mt < 2; mt++)
#pragma unroll
    for (int ks = 0; ks < 4; ks++)
      qa[mt][ks] = *(const bf16x8_t*)(Qg + ((ks * 4 + l4) * 64 + row0[mt] + l15) * 8);

  float mi_r[2][4], li_r[2][4];
  f32x4_t oacc[2][8] = {};
#pragma unroll
  for (int mt = 0; mt < 2; mt++)
#pragma unroll
    for (int r = 0; r < 4; r++) { mi_r[mt][r] = -__builtin_inff(); li_r[mt][r] = 0.0f; }

#pragma unroll 1
  for (int j = 0; j < 12; j++) {
    if (!(keep_mask & (1 << j))) continue;
    int cj;
    if (j < 4) cj = j * 16;
    else { cj = qid - 11 + j; cj = cj < 0 ? 0 : cj; cj = cj > 63 ? 63 : cj; }

    __syncthreads();  // prior iter's K/V LDS reads done before overwrite
#pragma unroll
    for (int i = 0; i < 4; i++) {
      int f = t + 256 * i;
      load16(Kg + (size_t)cj * 8192 + (size_t)f * 8, Ks + (w * 64 + i * 256) * 8);
      load16(Vg + (size_t)cj * 8192 + (size_t)f * 8, Vs + (w * 64 + i * 256) * 8);
    }
    __syncthreads();  // K/V staged

    // S = Q K^T : per wave 2 row-tiles x 64 cols
    f32x4_t sacc[2][4] = {};
#pragma unroll
    for (int ks = 0; ks < 4; ks++)
#pragma unroll
      for (int ni = 0; ni < 4; ni++) {
        bf16x8_t kb = *(const bf16x8_t*)&Ks[((ks * 4 + l4) * 64 + ni * 16 + l15) * 8];
#pragma unroll
        for (int mt = 0; mt < 2; mt++)
          sacc[mt][ni] = __builtin_amdgcn_mfma_f32_16x16x32_bf16(qa[mt][ks], kb, sacc[mt][ni], 0, 0, 0);
      }

    const bool diag = (cj == qid);
#pragma unroll
    for (int mt = 0; mt < 2; mt++) {
      float sv[4][4];
#pragma unroll
      for (int ni = 0; ni < 4; ni++)
#pragma unroll
        for (int r = 0; r < 4; r++) {
          float x = sacc[mt][ni][r] * SCALE_;
          if (diag && (ni * 16 + l15) > (row0[mt] + l4 * 4 + r)) x += NEG_;
          sv[ni][r] = x;
        }

      float rmax[4], rsum[4], alpha[4], p[4][4];
#pragma unroll
      for (int r = 0; r < 4; r++)
        rmax[r] = fmaxf(fmaxf(sv[0][r], sv[1][r]), fmaxf(sv[2][r], sv[3][r]));
#pragma unroll
      for (int msk = 1; msk < 16; msk <<= 1)
#pragma unroll
        for (int r = 0; r < 4; r++)
          rmax[r] = fmaxf(rmax[r], __shfl_xor(rmax[r], msk, 64));
#pragma unroll
      for (int r = 0; r < 4; r++) {
        float nm = fmaxf(mi_r[mt][r], rmax[r]);
        alpha[r] = __expf(mi_r[mt][r] - nm);
        mi_r[mt][r] = nm;
      }
#pragma unroll
      for (int ni = 0; ni < 4; ni++)
#pragma unroll
        for (int r = 0; r < 4; r++)
          p[ni][r] = __expf(sv[ni][r] - mi_r[mt][r]);
#pragma unroll
      for (int r = 0; r < 4; r++)
        rsum[r] = (p[0][r] + p[1][r]) + (p[2][r] + p[3][r]);
#pragma unroll
      for (int msk = 1; msk < 16; msk <<= 1)
#pragma unroll
        for (int r = 0; r < 4; r++)
          rsum[r] += __shfl_xor(rsum[r], msk, 64);
#pragma unroll
      for (int r = 0; r < 4; r++)
        li_r[mt][r] = li_r[mt][r] * alpha[r] + rsum[r];
#pragma unroll
      for (int n2 = 0; n2 < 8; n2++)
#pragma unroll
        for (int r = 0; r < 4; r++)
          oacc[mt][n2][r] *= alpha[r];

      // P: C-layout -> per-wave padded LDS tile (same wave: ds-order guarantees safety)
#pragma unroll
      for (int ni = 0; ni < 4; ni++)
#pragma unroll
        for (int r = 0; r < 4; r++)
          Ps[w * 1152 + (l4 * 4 + r) * 72 + ni * 16 + l15] = (bf16_t)p[ni][r];

      // O(mt) += P(mt) @ V
#pragma unroll
      for (int kst = 0; kst < 2; kst++) {
        bf16x8_t pa = *(const bf16x8_t*)&Ps[w * 1152 + l15 * 72 + kst * 32 + l4 * 8];
#pragma unroll
        for (int n2 = 0; n2 < 8; n2++) {
          bf16x8_t vb = *(const bf16x8_t*)&Vs[((kst * 4 + l4) * 128 + n2 * 16 + l15) * 8];
          oacc[mt][n2] = __builtin_amdgcn_mfma_f32_16x16x32_bf16(pa, vb, oacc[mt][n2], 0, 0, 0);
        }
      }
    }
  }

#pragma unroll
  for (int mt = 0; mt < 2; mt++) {
    float invl[4];
#pragma unroll
    for (int r = 0; r < 4; r++) invl[r] = 1.0f / li_r[mt][r];
#pragma unroll
    for (int n2 = 0; n2 < 8; n2++)
#pragma unroll
      for (int r = 0; r < 4; r++) {
        int m = row0[mt] + l4 * 4 + r;   // row within this head's 64-token block
        size_t idx = ((size_t)(b * S_ + qid * 64 + m)) * (NH_ * D_) + h * D_ + n2 * 16 + l15;
        Ao[idx] = (bf16_t)(oacc[mt][n2][r] * invl[r]);
      }
  }
}

// ---------------- launch ----------------
extern "C" void kernel_launch(void* const* d_in, const int* in_sizes, int n_in,
                              void* d_out, int out_size, void* d_ws, size_t ws_size,
                              hipStream_t stream) {
  const float* hs = (const float*)d_in[0];
  const float* cosp = (const float*)d_in[1];
  const float* sinp = (const float*)d_in[2];
  const float* Wq = (const float*)d_in[3];
  const float* Wk = (const float*)d_in[4];
  const float* Wv = (const float*)d_in[5];
  const float* Wo = (const float*)d_in[6];
  float* outp = (float*)d_out;

  char* ws = (char*)d_ws;
  bf16_t* Xb   = (bf16_t*)(ws);                 // 33,554,432 B (8192x2048)
  bf16_t* Wb   = (bf16_t*)(ws + 33554432);      // 12,582,912 B (3072x2048)
  bf16_t* Wob  = (bf16_t*)(ws + 46137344);      //  8,388,608 B (2048x2048)
  bf16_t* QKVo = (bf16_t*)(ws + 54525952);      // 50,331,648 B (8192x3072)
  bf16_t* Qr   = (bf16_t*)(ws + 104857600);     // 33,554,432 B (swizzled)
  bf16_t* Kr   = (bf16_t*)(ws + 138412032);     //  8,388,608 B (swizzled)
  bf16_t* Vt   = (bf16_t*)(ws + 146800640);     //  8,388,608 B (swizzled)
  bf16_t* Ao   = QKVo;                          // alias: QKVo fully consumed before attn

  // fused fp32 -> bf16 converts (one launch)
  cvt_all_kernel<<<dim3(26624), dim3(256), 0, stream>>>(hs, Wq, Wk, Wv, Wo, Xb, Wb, Wob);

  // QKV projection: (8192x2048) @ (3072x2048)^T -> bf16
  gemm_bt_kernel<1><<<dim3(64, 24), dim3(256), 0, stream>>>(Xb, Wb, (float*)nullptr, QKVo,
                                                            8192, 3072, 2048);
  // RoPE + swizzled head layouts
  rope_kernel<<<dim3(8192), dim3(320), 0, stream>>>(QKVo, cosp, sinp, Qr, Kr);
  vtrans_kernel<<<dim3(64, NKV_, B_), dim3(256), 0, stream>>>((const u16*)QKVo, (u16*)Vt);
  // GQA-packed block-sparse attention (2 heads per WG)
  attn_kernel<<<dim3(64, NKV_ * 2, B_), dim3(256), 0, stream>>>(Qr, Kr, Vt, Ao);
  // output projection: (8192x2048) @ (2048x2048)^T -> fp32 d_out
  gemm_bt_kernel<0><<<dim3(64, 16), dim3(256), 0, stream>>>(Ao, Wob, outp, (bf16_t*)nullptr,
                                                            8192, 2048, 2048);
}

// Round 6
// 525.927 us; speedup vs baseline: 1.0418x; 1.0418x over previous
//
#include <hip/hip_runtime.h>

typedef __bf16 bf16_t;
typedef __bf16 bf16x8_t __attribute__((ext_vector_type(8)));
typedef __bf16 bf16x4_t __attribute__((ext_vector_type(4)));
typedef float f32x4_t __attribute__((ext_vector_type(4)));
typedef unsigned short u16;
typedef unsigned int u32;

#define B_ 2
#define S_ 4096
#define NH_ 16
#define NKV_ 4
#define D_ 128
#define NEG_ (-1000000000.0f)
#define SCALE_ 0.08838834764831845f

// async global->LDS, 16B per lane; LDS dest must be wave-uniform base (+lane*16 implicit)
__device__ __forceinline__ void load16(const bf16_t* g, bf16_t* l) {
  __builtin_amdgcn_global_load_lds(
      (__attribute__((address_space(1))) void*)(g),
      (__attribute__((address_space(3))) void*)(l),
      16, 0, 0);
}

// ---------------- fused fp32 -> bf16 convert (all 5 tensors, one launch) ----------------
__global__ __launch_bounds__(256) void cvt_all_kernel(const float* __restrict__ hs,
                                                      const float* __restrict__ Wq,
                                                      const float* __restrict__ Wk,
                                                      const float* __restrict__ Wv,
                                                      const float* __restrict__ Wo,
                                                      bf16_t* __restrict__ Xb,
                                                      bf16_t* __restrict__ Wb,
                                                      bf16_t* __restrict__ Wob) {
  int i = blockIdx.x * 256 + threadIdx.x;  // float4 index; ranges are 256-aligned (uniform branch)
  const float* src; bf16_t* dst; int local;
  if (i < 4194304)      { src = hs; dst = Xb;            local = i; }
  else if (i < 5242880) { src = Wq; dst = Wb;            local = i - 4194304; }
  else if (i < 5505024) { src = Wk; dst = Wb + 4194304;  local = i - 5242880; }
  else if (i < 5767168) { src = Wv; dst = Wb + 5242880;  local = i - 5505024; }
  else                  { src = Wo; dst = Wob;           local = i - 5767168; }
  float4 v = ((const float4*)src)[local];
  bf16x4_t o;
  o.x = (bf16_t)v.x; o.y = (bf16_t)v.y; o.z = (bf16_t)v.z; o.w = (bf16_t)v.w;
  *(bf16x4_t*)(dst + (size_t)local * 4) = o;
}

// ---------------- GEMM: C(MxN) = A(MxK) @ B(NxK)^T, bf16 in, fp32 acc ----------------
// m97 structure + XOR-swizzled LDS image: chunk (row,c) lives at slot c^((row>>1)&3)
// -> fragment ds_read_b128 is 2-way (free) instead of 8-way.
template <int BF16OUT>
__global__ __launch_bounds__(256) void gemm_bt_kernel(const bf16_t* __restrict__ A,
                                                      const bf16_t* __restrict__ Bm,
                                                      float* __restrict__ Cf,
                                                      bf16_t* __restrict__ Cb,
                                                      int M, int N, int K) {
  __shared__ bf16_t As[128 * 32];
  __shared__ bf16_t Bs[128 * 32];
  const int t = threadIdx.x;
  const int lane = t & 63;
  const int w = t >> 6;
  const int wr = w >> 1, wc = w & 1;
  const int l15 = lane & 15, l4 = lane >> 4;
  const int m0 = blockIdx.x * 128;
  const int n0 = blockIdx.y * 128;
  const int xr = (l15 >> 1) & 3;   // fragment-read XOR term

  f32x4_t acc[4][4] = {};

  for (int k0 = 0; k0 < K; k0 += 32) {
    __syncthreads();
#pragma unroll
    for (int i = 0; i < 2; i++) {
      int f = t + 256 * i;
      int row = f >> 2, cl = f & 3;
      int cg = cl ^ ((row >> 1) & 3);   // global chunk that belongs in LDS slot cl
      load16(A + (size_t)(m0 + row) * K + k0 + cg * 8, As + (w * 64 + i * 256) * 8);
      load16(Bm + (size_t)(n0 + row) * K + k0 + cg * 8, Bs + (w * 64 + i * 256) * 8);
    }
    __syncthreads();
    bf16x8_t af[4], bfr[4];
#pragma unroll
    for (int mi = 0; mi < 4; mi++) {
      int ra = wr * 64 + mi * 16 + l15;
      af[mi] = *(const bf16x8_t*)&As[(ra * 4 + (l4 ^ xr)) * 8];
    }
#pragma unroll
    for (int ni = 0; ni < 4; ni++) {
      int rb = wc * 64 + ni * 16 + l15;
      bfr[ni] = *(const bf16x8_t*)&Bs[(rb * 4 + (l4 ^ xr)) * 8];
    }
#pragma unroll
    for (int mi = 0; mi < 4; mi++)
#pragma unroll
      for (int ni = 0; ni < 4; ni++)
        acc[mi][ni] = __builtin_amdgcn_mfma_f32_16x16x32_bf16(af[mi], bfr[ni], acc[mi][ni], 0, 0, 0);
  }

#pragma unroll
  for (int mi = 0; mi < 4; mi++)
#pragma unroll
    for (int ni = 0; ni < 4; ni++)
#pragma unroll
      for (int r = 0; r < 4; r++) {
        int grow = m0 + wr * 64 + mi * 16 + l4 * 4 + r;
        int gcol = n0 + wc * 64 + ni * 16 + l15;
        float v = acc[mi][ni][r];
        if (BF16OUT) Cb[(size_t)grow * N + gcol] = (bf16_t)v;
        else Cf[(size_t)grow * N + gcol] = v;
      }
}

// ---------------- RoPE + swizzled head layout for q,k ----------------
// Qro per (b,h,sblock): [lc(16)][row(64)][8]  where lc = d/8  (16 KB per block)
__global__ __launch_bounds__(320) void rope_kernel(const bf16_t* __restrict__ qkv,
                                                   const float* __restrict__ cosp,
                                                   const float* __restrict__ sinp,
                                                   bf16_t* __restrict__ Qro,
                                                   bf16_t* __restrict__ Kro) {
  const int tk = blockIdx.x;      // 0..8191 token
  const int b = tk >> 12;
  const int s = tk & 4095;
  const int sblock = s >> 6, row = s & 63;
  const int idx = threadIdx.x;    // 0..319: 256 q-chunks + 64 k-chunks
  int head, lc;
  const bf16_t* base;
  bf16_t* outp;
  if (idx < 256) {
    head = idx >> 4; lc = idx & 15;
    base = qkv + (size_t)tk * 3072 + head * 128;
    outp = Qro + ((size_t)(b * NH_ + head) * 64 + sblock) * 8192;
  } else {
    int i2 = idx - 256;
    head = i2 >> 4; lc = i2 & 15;
    base = qkv + (size_t)tk * 3072 + 2048 + head * 128;
    outp = Kro + ((size_t)(b * NKV_ + head) * 64 + sblock) * 8192;
  }
  const int d0 = lc * 8;
  bf16x8_t x = *(const bf16x8_t*)(base + d0);
  const int d0p = (d0 < 64) ? d0 + 64 : d0 - 64;
  bf16x8_t xp = *(const bf16x8_t*)(base + d0p);
  const float sgn = (d0 < 64) ? -1.0f : 1.0f;
  const float* cb = cosp + (size_t)tk * 128 + d0;
  const float* sb = sinp + (size_t)tk * 128 + d0;
  bf16x8_t o;
#pragma unroll
  for (int e = 0; e < 8; e++)
    o[e] = (bf16_t)((float)x[e] * cb[e] + sgn * (float)xp[e] * sb[e]);
  *(bf16x8_t*)(outp + (lc * 64 + row) * 8) = o;
}

// ---------------- V transpose into swizzled layout ----------------
// Vt per (b,kh,sblock): [sc(8)][d(128)][8]  where chunk content e runs along s
__global__ __launch_bounds__(256) void vtrans_kernel(const u16* __restrict__ qkv,
                                                     u16* __restrict__ vt) {
  __shared__ u16 tile[64][136];   // [s][d], d padded 128->136
  const int sblock = blockIdx.x;
  const int kh = blockIdx.y;
  const int b = blockIdx.z;
  const int t = threadIdx.x;
#pragma unroll
  for (int i = 0; i < 4; i++) {
    int f = t + 256 * i;
    int sl = f >> 4, c = f & 15;
    uint4 vv = *(const uint4*)(qkv + (size_t)(b * S_ + sblock * 64 + sl) * 3072 + 2560 + kh * 128 + c * 8);
    *(uint4*)&tile[sl][c * 8] = vv;
  }
  __syncthreads();
  u16* out = vt + ((size_t)(b * NKV_ + kh) * 64 + sblock) * 8192;
#pragma unroll
  for (int i = 0; i < 4; i++) {
    int g = t + 256 * i;
    int sc = g >> 7, d = g & 127;
    u16 e0 = tile[sc * 8 + 0][d], e1 = tile[sc * 8 + 1][d];
    u16 e2 = tile[sc * 8 + 2][d], e3 = tile[sc * 8 + 3][d];
    u16 e4 = tile[sc * 8 + 4][d], e5 = tile[sc * 8 + 5][d];
    u16 e6 = tile[sc * 8 + 6][d], e7 = tile[sc * 8 + 7][d];
    uint4 ov;
    ov.x = (u32)e0 | ((u32)e1 << 16);
    ov.y = (u32)e2 | ((u32)e3 << 16);
    ov.z = (u32)e4 | ((u32)e5 << 16);
    ov.w = (u32)e6 | ((u32)e7 << 16);
    *(uint4*)(out + (size_t)g * 8) = ov;
  }
}

// ---------------- GQA-packed block-sparse flash attention (double-buffered) ----------------
// one WG of 256 threads per (qblock, kv-head, head-pair, batch): 4 waves x 2
// row-tiles = 128 q-rows (2 heads x 64). K/V double-buffered in LDS, ONE barrier
// per K-block: prefetch j+1 right after the barrier, compute on j while loads fly.
// Row-sums via ones-column MFMA (no shuffle-reduce for l).
__global__ __launch_bounds__(256) void attn_kernel(const bf16_t* __restrict__ Qr,
                                                   const bf16_t* __restrict__ Kr,
                                                   const bf16_t* __restrict__ Vt,
                                                   bf16_t* __restrict__ Ao) {
  __shared__ bf16_t Ks[2][8192];         // 2 x 16 KB [lc16][row64][8]
  __shared__ bf16_t Vs[2][8192];         // 2 x 16 KB [sc8][d128][8]
  __shared__ bf16_t Ps[4 * 16 * 72];     // 9 KB: per-wave 16x72 padded, reused across mt
  const int qid = blockIdx.x;
  const int kh = blockIdx.y >> 1;
  const int hp = blockIdx.y & 1;
  const int b = blockIdx.z;
  const int t = threadIdx.x;
  const int lane = t & 63;
  const int w = t >> 6;                  // 0..3
  const int l15 = lane & 15, l4 = lane >> 4;
  const int h = kh * 4 + hp * 2 + (w >> 1);   // wave-uniform head
  int row0[2];
  row0[0] = ((w * 2) & 3) * 16;
  row0[1] = ((w * 2 + 1) & 3) * 16;

  // kept-block list (uniform per WG): [g0..g3, loc0..loc7], causal + dedup(first kept)
  int list[12];
  int nkeep = 0;
#pragma unroll
  for (int j = 0; j < 12; j++) {
    int cj;
    if (j < 4) cj = j * 16;
    else { cj = qid - 11 + j; cj = cj < 0 ? 0 : cj; cj = cj > 63 ? 63 : cj; }
    bool keep = (cj <= qid);
#pragma unroll
    for (int i = 0; i < j; i++) {
      int ci;
      if (i < 4) ci = i * 16;
      else { ci = qid - 11 + i; ci = ci < 0 ? 0 : ci; ci = ci > 63 ? 63 : ci; }
      if (ci == cj) keep = false;
    }
    if (keep) list[nkeep++] = cj;
  }

  const bf16_t* Qg = Qr + ((size_t)(b * NH_ + h) * 64 + qid) * 8192;
  const bf16_t* Kg = Kr + ((size_t)(b * NKV_ + kh) * 64) * 8192;
  const bf16_t* Vg = Vt + ((size_t)(b * NKV_ + kh) * 64) * 8192;

  // Q fragments straight from global (coalesced 256B runs), persistent
  bf16x8_t qa[2][4];
#pragma unroll
  for (int mt = 0; mt < 2; mt++)
#pragma unroll
    for (int ks = 0; ks < 4; ks++)
      qa[mt][ks] = *(const bf16x8_t*)(Qg + ((ks * 4 + l4) * 64 + row0[mt] + l15) * 8);

  bf16x8_t ones;
#pragma unroll
  for (int e = 0; e < 8; e++) ones[e] = (bf16_t)1.0f;

  float mi_r[2][4], li_r[2][4];
  f32x4_t oacc[2][8] = {};
#pragma unroll
  for (int mt = 0; mt < 2; mt++)
#pragma unroll
    for (int r = 0; r < 4; r++) { mi_r[mt][r] = -__builtin_inff(); li_r[mt][r] = 0.0f; }

  // prologue: stage first block into buffer 0
  {
    int cj = list[0];
#pragma unroll
    for (int i = 0; i < 4; i++) {
      int f = t + 256 * i;
      load16(Kg + (size_t)cj * 8192 + (size_t)f * 8, Ks[0] + (w * 64 + i * 256) * 8);
      load16(Vg + (size_t)cj * 8192 + (size_t)f * 8, Vs[0] + (w * 64 + i * 256) * 8);
    }
  }

  int cur = 0;
#pragma unroll 1
  for (int idx = 0; idx < nkeep; idx++) {
    const int cj = list[idx];
    __syncthreads();  // drains: buf[cur] loads complete; prev iter's LDS reads done
    // prefetch next block into the other buffer (lands during compute below)
    if (idx + 1 < nkeep) {
      int cn = list[idx + 1];
#pragma unroll
      for (int i = 0; i < 4; i++) {
        int f = t + 256 * i;
        load16(Kg + (size_t)cn * 8192 + (size_t)f * 8, Ks[cur ^ 1] + (w * 64 + i * 256) * 8);
        load16(Vg + (size_t)cn * 8192 + (size_t)f * 8, Vs[cur ^ 1] + (w * 64 + i * 256) * 8);
      }
    }
    const bf16_t* ks_ = Ks[cur];
    const bf16_t* vs_ = Vs[cur];

    // S = Q K^T : per wave 2 row-tiles x 64 cols
    f32x4_t sacc[2][4] = {};
#pragma unroll
    for (int ks = 0; ks < 4; ks++)
#pragma unroll
      for (int ni = 0; ni < 4; ni++) {
        bf16x8_t kb = *(const bf16x8_t*)&ks_[((ks * 4 + l4) * 64 + ni * 16 + l15) * 8];
#pragma unroll
        for (int mt = 0; mt < 2; mt++)
          sacc[mt][ni] = __builtin_amdgcn_mfma_f32_16x16x32_bf16(qa[mt][ks], kb, sacc[mt][ni], 0, 0, 0);
      }

    const bool diag = (cj == qid);
    float alpha[2][4];
#pragma unroll
    for (int mt = 0; mt < 2; mt++) {
      float sv[4][4];
#pragma unroll
      for (int ni = 0; ni < 4; ni++)
#pragma unroll
        for (int r = 0; r < 4; r++) {
          float x = sacc[mt][ni][r] * SCALE_;
          if (diag && (ni * 16 + l15) > (row0[mt] + l4 * 4 + r)) x += NEG_;
          sv[ni][r] = x;
        }

      float rmax[4];
#pragma unroll
      for (int r = 0; r < 4; r++)
        rmax[r] = fmaxf(fmaxf(sv[0][r], sv[1][r]), fmaxf(sv[2][r], sv[3][r]));
#pragma unroll
      for (int msk = 1; msk < 16; msk <<= 1)
#pragma unroll
        for (int r = 0; r < 4; r++)
          rmax[r] = fmaxf(rmax[r], __shfl_xor(rmax[r], msk, 64));
#pragma unroll
      for (int r = 0; r < 4; r++) {
        float nm = fmaxf(mi_r[mt][r], rmax[r]);
        alpha[mt][r] = __expf(mi_r[mt][r] - nm);
        mi_r[mt][r] = nm;
      }
      float p[4][4];
#pragma unroll
      for (int ni = 0; ni < 4; ni++)
#pragma unroll
        for (int r = 0; r < 4; r++)
          p[ni][r] = __expf(sv[ni][r] - mi_r[mt][r]);
      // P: C-layout -> per-wave padded LDS tile (same wave, sequential across mt)
#pragma unroll
      for (int ni = 0; ni < 4; ni++)
#pragma unroll
        for (int r = 0; r < 4; r++)
          Ps[w * 1152 + (l4 * 4 + r) * 72 + ni * 16 + l15] = (bf16_t)p[ni][r];
      // rescale O by alpha
#pragma unroll
      for (int n2 = 0; n2 < 8; n2++)
#pragma unroll
        for (int r = 0; r < 4; r++)
          oacc[mt][n2][r] *= alpha[mt][r];

      // O(mt) += P(mt) @ V ; row-sums via ones-MFMA (C-layout matches oacc lanes)
      f32x4_t lacc = {};
#pragma unroll
      for (int kst = 0; kst < 2; kst++) {
        bf16x8_t pa = *(const bf16x8_t*)&Ps[w * 1152 + l15 * 72 + kst * 32 + l4 * 8];
        lacc = __builtin_amdgcn_mfma_f32_16x16x32_bf16(pa, ones, lacc, 0, 0, 0);
#pragma unroll
        for (int n2 = 0; n2 < 8; n2++) {
          bf16x8_t vb = *(const bf16x8_t*)&vs_[((kst * 4 + l4) * 128 + n2 * 16 + l15) * 8];
          oacc[mt][n2] = __builtin_amdgcn_mfma_f32_16x16x32_bf16(pa, vb, oacc[mt][n2], 0, 0, 0);
        }
      }
#pragma unroll
      for (int r = 0; r < 4; r++)
        li_r[mt][r] = li_r[mt][r] * alpha[mt][r] + lacc[r];
    }

    cur ^= 1;
  }

#pragma unroll
  for (int mt = 0; mt < 2; mt++) {
    float invl[4];
#pragma unroll
    for (int r = 0; r < 4; r++) invl[r] = 1.0f / li_r[mt][r];
#pragma unroll
    for (int n2 = 0; n2 < 8; n2++)
#pragma unroll
      for (int r = 0; r < 4; r++) {
        int m = row0[mt] + l4 * 4 + r;   // row within this head's 64-token block
        size_t idx = ((size_t)(b * S_ + qid * 64 + m)) * (NH_ * D_) + h * D_ + n2 * 16 + l15;
        Ao[idx] = (bf16_t)(oacc[mt][n2][r] * invl[r]);
      }
  }
}

// ---------------- launch ----------------
extern "C" void kernel_launch(void* const* d_in, const int* in_sizes, int n_in,
                              void* d_out, int out_size, void* d_ws, size_t ws_size,
                              hipStream_t stream) {
  const float* hs = (const float*)d_in[0];
  const float* cosp = (const float*)d_in[1];
  const float* sinp = (const float*)d_in[2];
  const float* Wq = (const float*)d_in[3];
  const float* Wk = (const float*)d_in[4];
  const float* Wv = (const float*)d_in[5];
  const float* Wo = (const float*)d_in[6];
  float* outp = (float*)d_out;

  char* ws = (char*)d_ws;
  bf16_t* Xb   = (bf16_t*)(ws);                 // 33,554,432 B (8192x2048)
  bf16_t* Wb   = (bf16_t*)(ws + 33554432);      // 12,582,912 B (3072x2048)
  bf16_t* Wob  = (bf16_t*)(ws + 46137344);      //  8,388,608 B (2048x2048)
  bf16_t* QKVo = (bf16_t*)(ws + 54525952);      // 50,331,648 B (8192x3072)
  bf16_t* Qr   = (bf16_t*)(ws + 104857600);     // 33,554,432 B (swizzled)
  bf16_t* Kr   = (bf16_t*)(ws + 138412032);     //  8,388,608 B (swizzled)
  bf16_t* Vt   = (bf16_t*)(ws + 146800640);     //  8,388,608 B (swizzled)
  bf16_t* Ao   = QKVo;                          // alias: QKVo fully consumed before attn

  // fused fp32 -> bf16 converts (one launch)
  cvt_all_kernel<<<dim3(26624), dim3(256), 0, stream>>>(hs, Wq, Wk, Wv, Wo, Xb, Wb, Wob);

  // QKV projection: (8192x2048) @ (3072x2048)^T -> bf16
  gemm_bt_kernel<1><<<dim3(64, 24), dim3(256), 0, stream>>>(Xb, Wb, (float*)nullptr, QKVo,
                                                            8192, 3072, 2048);
  // RoPE + swizzled head layouts
  rope_kernel<<<dim3(8192), dim3(320), 0, stream>>>(QKVo, cosp, sinp, Qr, Kr);
  vtrans_kernel<<<dim3(64, NKV_, B_), dim3(256), 0, stream>>>((const u16*)QKVo, (u16*)Vt);
  // GQA-packed block-sparse attention (2 heads per WG, double-buffered K/V)
  attn_kernel<<<dim3(64, NKV_ * 2, B_), dim3(256), 0, stream>>>(Qr, Kr, Vt, Ao);
  // output projection: (8192x2048) @ (2048x2048)^T -> fp32 d_out
  gemm_bt_kernel<0><<<dim3(64, 16), dim3(256), 0, stream>>>(Ao, Wob, outp, (bf16_t*)nullptr,
                                                            8192, 2048, 2048);
}